// Round 4
// baseline (3646.601 us; speedup 1.0000x reference)
//
#include <hip/hip_runtime.h>

#define N_ROWS 4096
#define D_DIM  2048
#define V_DIM  32000

typedef unsigned char  u8;
typedef __attribute__((ext_vector_type(4)))  int   i32x4;
typedef __attribute__((ext_vector_type(8)))  int   i32x8;
typedef __attribute__((ext_vector_type(16))) float f32x16;

__device__ __forceinline__ unsigned pack4_fp8(float a, float b, float c, float d) {
    unsigned w = __builtin_amdgcn_cvt_pk_fp8_f32(a, b, 0, false);   // bytes 0,1
    w = __builtin_amdgcn_cvt_pk_fp8_f32(c, d, w, true);             // bytes 2,3
    return w;
}
__device__ __forceinline__ u8 f2fp8(float a) {
    return (u8)(__builtin_amdgcn_cvt_pk_fp8_f32(a, a, 0, false) & 0xFF);
}

// ---- zero the per-row accumulators ----
__global__ void init_acc(float* __restrict__ p, int n) {
    int i = blockIdx.x * blockDim.x + threadIdx.x;
    if (i < n) p[i] = 0.0f;
}

// ---- convert input A fp32 [N,D] -> fp8 e4m3 [N,D] ----
__global__ void convert_a_fp8(const float4* __restrict__ in, uint4* __restrict__ out, int n16) {
    int i = blockIdx.x * blockDim.x + threadIdx.x;
    int stride = gridDim.x * blockDim.x;
    for (; i < n16; i += stride) {
        float4 v0 = in[i * 4 + 0], v1 = in[i * 4 + 1];
        float4 v2 = in[i * 4 + 2], v3 = in[i * 4 + 3];
        uint4 o;
        o.x = pack4_fp8(v0.x, v0.y, v0.z, v0.w);
        o.y = pack4_fp8(v1.x, v1.y, v1.z, v1.w);
        o.z = pack4_fp8(v2.x, v2.y, v2.z, v2.w);
        o.w = pack4_fp8(v3.x, v3.y, v3.z, v3.w);
        out[i] = o;
    }
}

// ---- transpose-convert weight fp32 [D,V] -> fp8 Wt [V,D] ----
__global__ __launch_bounds__(256) void transpose_w_fp8(const float* __restrict__ W,
                                                       u8* __restrict__ Wt) {
    __shared__ u8 tile[64 * 64];
    const int v0 = blockIdx.x * 64;
    const int d0 = blockIdx.y * 64;
    const int tid = threadIdx.x;

    const int vch = (tid & 15) * 4;
    const int dr0 = tid >> 4;
#pragma unroll
    for (int i = 0; i < 4; ++i) {
        int d = dr0 + i * 16;
        float4 w = *(const float4*)&W[(size_t)(d0 + d) * V_DIM + v0 + vch];
        float wv[4] = {w.x, w.y, w.z, w.w};
#pragma unroll
        for (int j = 0; j < 4; ++j) {
            int v = vch + j;
            int slot = (d >> 4) ^ ((v >> 2) & 3);
            tile[v * 64 + slot * 16 + (d & 15)] = f2fp8(wv[j]);
        }
    }
    __syncthreads();

    const int v = tid >> 2, s = tid & 3;
    const int c = s ^ ((v >> 2) & 3);
    uint4 val = *(const uint4*)&tile[tid * 16];
    *(uint4*)&Wt[(size_t)(v0 + v) * D_DIM + d0 + c * 16] = val;
}

// ---- fused fp8 GEMM (MX-scaled 32x32x64 MFMA, unit scales) + softcap + CE partials ----
// C-tile 128x128, BK=128, 4 waves 2x2; per wave 2x2 of 32x32x64 MFMAs (64x64 tile).
// LDS row = 128 B = 8 chunks of 16 B; global chunk g of row r stored at slot g ^ (r&7).
__global__ __launch_bounds__(256, 3) void gemm_ce(
    const u8* __restrict__ A, const u8* __restrict__ Wt,
    const int* __restrict__ targets,
    float* __restrict__ sumexp, float* __restrict__ sumlog, float* __restrict__ tlogit)
{
    __shared__ u8 lsA[128 * 128];
    __shared__ u8 lsB[128 * 128];

    const int tid  = threadIdx.x;
    const int lane = tid & 63;
    const int wave = tid >> 6;
    const int wr   = wave >> 1, wc = wave & 1;
    const int m    = lane & 31, half = lane >> 5;

    const int rowbase = blockIdx.x * 128;
    const int colbase = blockIdx.y * 128;

    f32x16 acc[2][2];
#pragma unroll
    for (int i = 0; i < 2; ++i)
#pragma unroll
        for (int j = 0; j < 2; ++j)
            acc[i][j] = (f32x16)(0.0f);

    // staging: chunk c = tid + 256*i -> row r = (tid>>3) + 32*i, slot tid&7,
    // fetches global chunk g = (tid&7) ^ ((tid>>3)&7)  (invariant in i)
    const int r0  = tid >> 3;
    const int g16 = (((tid & 7) ^ (r0 & 7))) * 16;
    const u8* gA = A  + (size_t)(rowbase + r0) * D_DIM + g16;
    const u8* gB = Wt + (size_t)(colbase + r0) * D_DIM + g16;
    u8* lA = &lsA[tid * 16];
    u8* lB = &lsB[tid * 16];

    // frag-read LDS byte addresses. Lane reads rows rA/rB, k-bytes
    // [h*64 + half*32, +32) = global chunks {h*4+half*2, h*4+half*2+1},
    // each at slot g ^ (row&7); row&7 == m&7 (wr*64, tr*32 are 0 mod 8).
    const int rA = wr * 64 + m;
    const int rB = wc * 64 + m;
    const int sw = m & 7;
    int aA[4], aB[4];
#pragma unroll
    for (int j = 0; j < 4; ++j) {
        int g = half * 2 + (j & 1) + (j >> 1) * 4;   // j = h*2 + b
        aA[j] = rA * 128 + ((g ^ sw) * 16);
        aB[j] = rB * 128 + ((g ^ sw) * 16);
    }

    for (int kt = 0; kt < D_DIM / 128; ++kt) {
        const int ko = kt * 128;
#pragma unroll
        for (int i = 0; i < 4; ++i) {
            __builtin_amdgcn_global_load_lds(
                (const __attribute__((address_space(1))) void*)(gA + (size_t)i * 32 * D_DIM + ko),
                (__attribute__((address_space(3))) void*)(lA + i * 4096), 16, 0, 0);
            __builtin_amdgcn_global_load_lds(
                (const __attribute__((address_space(1))) void*)(gB + (size_t)i * 32 * D_DIM + ko),
                (__attribute__((address_space(3))) void*)(lB + i * 4096), 16, 0, 0);
        }
        __syncthreads();

#pragma unroll
        for (int h = 0; h < 2; ++h) {
            i32x8 a0, a1, b0, b1;
            {
                i32x4 lo = *(const i32x4*)&lsA[aA[h * 2 + 0]];
                i32x4 hi = *(const i32x4*)&lsA[aA[h * 2 + 1]];
                a0 = __builtin_shufflevector(lo, hi, 0, 1, 2, 3, 4, 5, 6, 7);
            }
            {
                i32x4 lo = *(const i32x4*)&lsA[aA[h * 2 + 0] + 4096];
                i32x4 hi = *(const i32x4*)&lsA[aA[h * 2 + 1] + 4096];
                a1 = __builtin_shufflevector(lo, hi, 0, 1, 2, 3, 4, 5, 6, 7);
            }
            {
                i32x4 lo = *(const i32x4*)&lsB[aB[h * 2 + 0]];
                i32x4 hi = *(const i32x4*)&lsB[aB[h * 2 + 1]];
                b0 = __builtin_shufflevector(lo, hi, 0, 1, 2, 3, 4, 5, 6, 7);
            }
            {
                i32x4 lo = *(const i32x4*)&lsB[aB[h * 2 + 0] + 4096];
                i32x4 hi = *(const i32x4*)&lsB[aB[h * 2 + 1] + 4096];
                b1 = __builtin_shufflevector(lo, hi, 0, 1, 2, 3, 4, 5, 6, 7);
            }
            acc[0][0] = __builtin_amdgcn_mfma_scale_f32_32x32x64_f8f6f4(
                a0, b0, acc[0][0], 0, 0, 0, 0x7F7F7F7F, 0, 0x7F7F7F7F);
            acc[0][1] = __builtin_amdgcn_mfma_scale_f32_32x32x64_f8f6f4(
                a0, b1, acc[0][1], 0, 0, 0, 0x7F7F7F7F, 0, 0x7F7F7F7F);
            acc[1][0] = __builtin_amdgcn_mfma_scale_f32_32x32x64_f8f6f4(
                a1, b0, acc[1][0], 0, 0, 0, 0x7F7F7F7F, 0, 0x7F7F7F7F);
            acc[1][1] = __builtin_amdgcn_mfma_scale_f32_32x32x64_f8f6f4(
                a1, b1, acc[1][1], 0, 0, 0, 0x7F7F7F7F, 0, 0x7F7F7F7F);
        }
        __syncthreads();
    }

    // ---- epilogue: 32x32 C/D layout col=lane&31, row=(reg&3)+8*(reg>>2)+4*half ----
#pragma unroll
    for (int tr = 0; tr < 2; ++tr) {
        int rows[16], tgt[16];
        float se[16], sl[16];
#pragma unroll
        for (int g = 0; g < 16; ++g) {
            rows[g] = rowbase + wr * 64 + tr * 32 + (g & 3) + 8 * (g >> 2) + 4 * half;
            tgt[g]  = targets[rows[g]];
            se[g] = 0.f; sl[g] = 0.f;
        }
#pragma unroll
        for (int tc = 0; tc < 2; ++tc) {
            int gcol = colbase + wc * 64 + tc * 32 + m;
            f32x16 v = acc[tr][tc];
#pragma unroll
            for (int g = 0; g < 16; ++g) {
                float a  = v[g];
                float e2 = __expf(a * (2.0f / 30.0f));     // exp(2*a/30)
                float th = 1.0f - 2.0f / (e2 + 1.0f);      // tanh(a/30)
                float l  = 30.0f * th;
                float el = __expf(l);
                se[g] += el;
                sl[g] += l;
                if (tgt[g] == gcol) tlogit[rows[g]] = l;   // unique writer
            }
        }
#pragma unroll
        for (int g = 0; g < 16; ++g) {
            float e = se[g], s = sl[g];
#pragma unroll
            for (int off = 1; off < 32; off <<= 1) {
                e += __shfl_xor(e, off);
                s += __shfl_xor(s, off);
            }
            if (m == 0) {
                atomicAdd(&sumexp[rows[g]], e);
                atomicAdd(&sumlog[rows[g]], s);
            }
        }
    }
}

// ---- final scalar reduction ----
__global__ void finalize(const float* __restrict__ sumexp, const float* __restrict__ sumlog,
                         const float* __restrict__ tlogit, const int* __restrict__ targets,
                         float* __restrict__ out)
{
    const int tid = threadIdx.x;
    float acc = 0.f, cnt = 0.f;
    for (int r = tid; r < N_ROWS; r += 256) {
        int tg = targets[r];
        if (tg != -100) {
            float lse    = __logf(sumexp[r]);
            float nll    = lse - tlogit[r];
            float smooth = lse - sumlog[r] * (1.0f / V_DIM);
            float ce     = 0.9f * nll + 0.1f * smooth;
            float z      = 1e-4f * lse * lse;
            acc += ce + z;
            cnt += 1.f;
        }
    }
#pragma unroll
    for (int off = 1; off < 64; off <<= 1) {
        acc += __shfl_xor(acc, off);
        cnt += __shfl_xor(cnt, off);
    }
    __shared__ float sa[4], sc[4];
    if ((tid & 63) == 0) { sa[tid >> 6] = acc; sc[tid >> 6] = cnt; }
    __syncthreads();
    if (tid == 0) {
        float t = sa[0] + sa[1] + sa[2] + sa[3];
        float c = sc[0] + sc[1] + sc[2] + sc[3];
        out[0] = t / c;
    }
}

extern "C" void kernel_launch(void* const* d_in, const int* in_sizes, int n_in,
                              void* d_out, int out_size, void* d_ws, size_t ws_size,
                              hipStream_t stream) {
    const float* A  = (const float*)d_in[0];   // [4096, 2048]
    const float* W  = (const float*)d_in[1];   // [2048, 32000]
    const int*   tg = (const int*)d_in[2];     // [4096]
    float* out = (float*)d_out;

    char* ws = (char*)d_ws;
    u8* A8 = (u8*)ws;
    size_t off = (size_t)N_ROWS * D_DIM;                    // 8 MB
    u8* Wt8 = (u8*)(ws + off);
    off += (size_t)V_DIM * D_DIM;                           // 64 MB
    float* sumexp = (float*)(ws + off); off += (size_t)N_ROWS * sizeof(float);
    float* sumlog = (float*)(ws + off); off += (size_t)N_ROWS * sizeof(float);
    float* tlog   = (float*)(ws + off); off += (size_t)N_ROWS * sizeof(float);

    init_acc<<<dim3((N_ROWS * 3 + 255) / 256), 256, 0, stream>>>(sumexp, N_ROWS * 3);
    convert_a_fp8<<<dim3(512), 256, 0, stream>>>((const float4*)A, (uint4*)A8,
                                                 N_ROWS * D_DIM / 16);
    transpose_w_fp8<<<dim3(V_DIM / 64, D_DIM / 64), 256, 0, stream>>>(W, Wt8);
    gemm_ce<<<dim3(N_ROWS / 128, V_DIM / 128), 256, 0, stream>>>(A8, Wt8, tg,
                                                                 sumexp, sumlog, tlog);
    finalize<<<1, 256, 0, stream>>>(sumexp, sumlog, tlog, tg, out);
}

// Round 5
// 762.280 us; speedup vs baseline: 4.7838x; 4.7838x over previous
//
#include <hip/hip_runtime.h>

#define N_ROWS 4096
#define D_DIM  2048
#define V_DIM  32000

typedef unsigned char u8;
typedef __attribute__((ext_vector_type(2))) long  i64x2;
typedef __attribute__((ext_vector_type(4))) float f32x4;

__device__ __forceinline__ unsigned pack4_fp8(float a, float b, float c, float d) {
    unsigned w = __builtin_amdgcn_cvt_pk_fp8_f32(a, b, 0, false);   // bytes 0,1
    w = __builtin_amdgcn_cvt_pk_fp8_f32(c, d, w, true);             // bytes 2,3
    return w;
}
__device__ __forceinline__ u8 f2fp8(float a) {
    return (u8)(__builtin_amdgcn_cvt_pk_fp8_f32(a, a, 0, false) & 0xFF);
}

// ---- zero the per-row accumulators ----
__global__ void init_acc(float* __restrict__ p, int n) {
    int i = blockIdx.x * blockDim.x + threadIdx.x;
    if (i < n) p[i] = 0.0f;
}

// ---- convert A fp32 [N,D] -> fp8, k-packed: 16B chunk q of each 64B k-group
// holds k-bytes [g*64+q*8, +8) ++ [g*64+32+q*8, +8)  (quad q's kstep0/kstep1) ----
__global__ void convert_a_fp8(const float4* __restrict__ in, uint4* __restrict__ out,
                              int nchunks) {
    int i = blockIdx.x * blockDim.x + threadIdx.x;
    int stride = gridDim.x * blockDim.x;
    for (; i < nchunks; i += stride) {
        int g = i >> 2, q = i & 3;
        int f4 = g * 16 + q * 2;
        float4 a0 = in[f4],     a1 = in[f4 + 1];
        float4 b0 = in[f4 + 8], b1 = in[f4 + 9];
        uint4 o;
        o.x = pack4_fp8(a0.x, a0.y, a0.z, a0.w);
        o.y = pack4_fp8(a1.x, a1.y, a1.z, a1.w);
        o.z = pack4_fp8(b0.x, b0.y, b0.z, b0.w);
        o.w = pack4_fp8(b1.x, b1.y, b1.z, b1.w);
        out[i] = o;
    }
}

// ---- transpose-convert W fp32 [D,V] -> fp8 Wt [V,D], same k-packing along D ----
__global__ __launch_bounds__(256) void transpose_w_fp8(const float* __restrict__ W,
                                                       u8* __restrict__ Wt) {
    __shared__ u8 tile[64][72];              // plain tile, +8 pad (8B-aligned rows)
    const int v0 = blockIdx.x * 64;
    const int d0 = blockIdx.y * 64;
    const int tid = threadIdx.x;

    const int vch = (tid & 15) * 4;
    const int dr0 = tid >> 4;
#pragma unroll
    for (int i = 0; i < 4; ++i) {
        int d = dr0 + i * 16;
        float4 w = *(const float4*)&W[(size_t)(d0 + d) * V_DIM + v0 + vch];
        tile[vch + 0][d] = f2fp8(w.x);
        tile[vch + 1][d] = f2fp8(w.y);
        tile[vch + 2][d] = f2fp8(w.z);
        tile[vch + 3][d] = f2fp8(w.w);
    }
    __syncthreads();

    // one packed 16B chunk per thread: v = tid>>2, q = tid&3
    const int v = tid >> 2, q = tid & 3;
    uint2 lo = *(const uint2*)&tile[v][q * 8];        // kstep0 piece
    uint2 hi = *(const uint2*)&tile[v][32 + q * 8];   // kstep1 piece
    uint4 o = make_uint4(lo.x, lo.y, hi.x, hi.y);
    *(uint4*)&Wt[(size_t)(v0 + v) * D_DIM + d0 + q * 16] = o;
}

// ---- fused fp8 GEMM (plain 16x16x32 fp8 MFMA) + softcap + CE partials ----
// C-tile 128x128, BK=128 (4 ksteps), 4 waves 2x2, wave = 4x4 of 16x16 MFMAs.
// LDS row = 128 B = 8 chunks of 16 B; chunk g of row r at slot g ^ (r&7)
// (bank base 4*slot covers all 8 phases -> conflict-free b128 frag reads).
__global__ __launch_bounds__(256) void gemm_ce(
    const u8* __restrict__ A, const u8* __restrict__ Wt,
    const int* __restrict__ targets,
    float* __restrict__ sumexp, float* __restrict__ sumlog, float* __restrict__ tlogit)
{
    __shared__ u8 lsA[128 * 128];
    __shared__ u8 lsB[128 * 128];

    const int tid   = threadIdx.x;
    const int lane  = tid & 63;
    const int wave  = tid >> 6;
    const int wr    = wave >> 1, wc = wave & 1;
    const int col16 = lane & 15, quad = lane >> 4;

    const int rowbase = blockIdx.x * 128;
    const int colbase = blockIdx.y * 128;

    f32x4 acc[4][4];
#pragma unroll
    for (int i = 0; i < 4; ++i)
#pragma unroll
        for (int j = 0; j < 4; ++j)
            acc[i][j] = (f32x4){0.f, 0.f, 0.f, 0.f};

    // staging: chunk c = tid + 256*i -> row r = (tid>>3)+32*i, slot tid&7,
    // global chunk g = (tid&7) ^ (r&7)   (invariant in i since 32 ≡ 0 mod 8)
    const int r0   = tid >> 3;
    const int goff = ((tid & 7) ^ (r0 & 7)) * 16;
    const u8* gA = A  + (size_t)(rowbase + r0) * D_DIM + goff;
    const u8* gB = Wt + (size_t)(colbase + r0) * D_DIM + goff;
    u8* lA = &lsA[tid * 16];
    u8* lB = &lsB[tid * 16];

    // frag bases: row rA = wr*64 + mi*16 + col16 (rA&7 == col16&7);
    // kpair0 chunk = quad, kpair1 chunk = quad+4 -> addr XOR 64
    const int sw    = col16 & 7;
    const int baseA = (wr * 64 + col16) * 128 + ((quad ^ sw) * 16);
    const int baseB = (wc * 64 + col16) * 128 + ((quad ^ sw) * 16);

    for (int kt = 0; kt < D_DIM / 128; ++kt) {
        const int ko = kt * 128;
#pragma unroll
        for (int i = 0; i < 4; ++i) {
            __builtin_amdgcn_global_load_lds(
                (const __attribute__((address_space(1))) void*)(gA + (size_t)i * 32 * D_DIM + ko),
                (__attribute__((address_space(3))) void*)(lA + i * 4096), 16, 0, 0);
            __builtin_amdgcn_global_load_lds(
                (const __attribute__((address_space(1))) void*)(gB + (size_t)i * 32 * D_DIM + ko),
                (__attribute__((address_space(3))) void*)(lB + i * 4096), 16, 0, 0);
        }
        __syncthreads();

        i64x2 aF0[4], aF1[4], bF0[4], bF1[4];
#pragma unroll
        for (int mi = 0; mi < 4; ++mi) {
            aF0[mi] = *(const i64x2*)&lsA[baseA + mi * 2048];
            aF1[mi] = *(const i64x2*)&lsA[(baseA + mi * 2048) ^ 64];
            bF0[mi] = *(const i64x2*)&lsB[baseB + mi * 2048];
            bF1[mi] = *(const i64x2*)&lsB[(baseB + mi * 2048) ^ 64];
        }

#pragma unroll
        for (int mi = 0; mi < 4; ++mi)
#pragma unroll
            for (int ni = 0; ni < 4; ++ni) {
                acc[mi][ni] = __builtin_amdgcn_mfma_f32_16x16x32_fp8_fp8(
                    aF0[mi].x, bF0[ni].x, acc[mi][ni], 0, 0, 0);
                acc[mi][ni] = __builtin_amdgcn_mfma_f32_16x16x32_fp8_fp8(
                    aF0[mi].y, bF0[ni].y, acc[mi][ni], 0, 0, 0);
                acc[mi][ni] = __builtin_amdgcn_mfma_f32_16x16x32_fp8_fp8(
                    aF1[mi].x, bF1[ni].x, acc[mi][ni], 0, 0, 0);
                acc[mi][ni] = __builtin_amdgcn_mfma_f32_16x16x32_fp8_fp8(
                    aF1[mi].y, bF1[ni].y, acc[mi][ni], 0, 0, 0);
            }
        __syncthreads();
    }

    // ---- epilogue: C/D layout col=lane&15, row=quad*4+reg (m89-verified) ----
#pragma unroll
    for (int mi = 0; mi < 4; ++mi) {
        int grows[4], tgts[4];
#pragma unroll
        for (int r = 0; r < 4; ++r) {
            grows[r] = rowbase + wr * 64 + mi * 16 + quad * 4 + r;
            tgts[r]  = targets[grows[r]];
        }
        float se[4] = {0.f, 0.f, 0.f, 0.f};
        float sl[4] = {0.f, 0.f, 0.f, 0.f};
#pragma unroll
        for (int ni = 0; ni < 4; ++ni) {
            int gcol = colbase + wc * 64 + ni * 16 + col16;
            f32x4 v = acc[mi][ni];
#pragma unroll
            for (int r = 0; r < 4; ++r) {
                float a  = v[r];
                float e2 = __expf(a * (2.0f / 30.0f));     // exp(2*a/30)
                float th = 1.0f - 2.0f / (e2 + 1.0f);      // tanh(a/30)
                float l  = 30.0f * th;
                float el = __expf(l);
                se[r] += el;
                sl[r] += l;
                if (tgts[r] == gcol) tlogit[grows[r]] = l; // unique writer
            }
        }
#pragma unroll
        for (int r = 0; r < 4; ++r) {
            float e = se[r], s = sl[r];
#pragma unroll
            for (int off = 1; off < 16; off <<= 1) {
                e += __shfl_xor(e, off);
                s += __shfl_xor(s, off);
            }
            if (col16 == 0) {
                atomicAdd(&sumexp[grows[r]], e);
                atomicAdd(&sumlog[grows[r]], s);
            }
        }
    }
}

// ---- final scalar reduction ----
__global__ void finalize(const float* __restrict__ sumexp, const float* __restrict__ sumlog,
                         const float* __restrict__ tlogit, const int* __restrict__ targets,
                         float* __restrict__ out)
{
    const int tid = threadIdx.x;
    float acc = 0.f, cnt = 0.f;
    for (int r = tid; r < N_ROWS; r += 256) {
        int tg = targets[r];
        if (tg != -100) {
            float lse    = __logf(sumexp[r]);
            float nll    = lse - tlogit[r];
            float smooth = lse - sumlog[r] * (1.0f / V_DIM);
            float ce     = 0.9f * nll + 0.1f * smooth;
            float z      = 1e-4f * lse * lse;
            acc += ce + z;
            cnt += 1.f;
        }
    }
#pragma unroll
    for (int off = 1; off < 64; off <<= 1) {
        acc += __shfl_xor(acc, off);
        cnt += __shfl_xor(cnt, off);
    }
    __shared__ float sa[4], sc[4];
    if ((tid & 63) == 0) { sa[tid >> 6] = acc; sc[tid >> 6] = cnt; }
    __syncthreads();
    if (tid == 0) {
        float t = sa[0] + sa[1] + sa[2] + sa[3];
        float c = sc[0] + sc[1] + sc[2] + sc[3];
        out[0] = t / c;
    }
}

extern "C" void kernel_launch(void* const* d_in, const int* in_sizes, int n_in,
                              void* d_out, int out_size, void* d_ws, size_t ws_size,
                              hipStream_t stream) {
    const float* A  = (const float*)d_in[0];   // [4096, 2048]
    const float* W  = (const float*)d_in[1];   // [2048, 32000]
    const int*   tg = (const int*)d_in[2];     // [4096]
    float* out = (float*)d_out;

    char* ws = (char*)d_ws;
    u8* A8 = (u8*)ws;
    size_t off = (size_t)N_ROWS * D_DIM;                    // 8 MB
    u8* Wt8 = (u8*)(ws + off);
    off += (size_t)V_DIM * D_DIM;                           // 64 MB
    float* sumexp = (float*)(ws + off); off += (size_t)N_ROWS * sizeof(float);
    float* sumlog = (float*)(ws + off); off += (size_t)N_ROWS * sizeof(float);
    float* tlog   = (float*)(ws + off); off += (size_t)N_ROWS * sizeof(float);

    init_acc<<<dim3((N_ROWS * 3 + 255) / 256), 256, 0, stream>>>(sumexp, N_ROWS * 3);
    convert_a_fp8<<<dim3(512), 256, 0, stream>>>((const float4*)A, (uint4*)A8,
                                                 N_ROWS * D_DIM / 16);
    transpose_w_fp8<<<dim3(V_DIM / 64, D_DIM / 64), 256, 0, stream>>>(W, Wt8);
    gemm_ce<<<dim3(N_ROWS / 128, V_DIM / 128), 256, 0, stream>>>(A8, Wt8, tg,
                                                                 sumexp, sumlog, tlog);
    finalize<<<1, 256, 0, stream>>>(sumexp, sumlog, tlog, tg, out);
}